// Round 6
// baseline (709.650 us; speedup 1.0000x reference)
//
#include <hip/hip_runtime.h>
#include <cstdint>
#include <cstddef>

typedef unsigned short u16;
using f16x8 = __attribute__((ext_vector_type(8))) _Float16;
using f32x4 = __attribute__((ext_vector_type(4))) float;
using u16x4 = __attribute__((ext_vector_type(4))) unsigned short;

// float -> fp16 bit pattern (round-to-nearest-even via v_cvt_f16_f32)
__device__ __forceinline__ u16 f2h(float f) {
  union { _Float16 h; u16 u; } c;
  c.h = (_Float16)f;
  return c.u;
}

// async global->LDS, 16B per lane. LDS dest must be wave-uniform base; HW writes base + lane*16.
__device__ __forceinline__ void gl_lds16(const void* g, void* lds) {
  __builtin_amdgcn_global_load_lds(
      (const __attribute__((address_space(1))) void*)(uintptr_t)g,
      (__attribute__((address_space(3))) void*)(uint32_t)(uintptr_t)lds,
      16, 0, 0);
}

// counted vmcnt wait (inline asm, literal immediate)
template <int N> __device__ __forceinline__ void vmcnt_wait() {
  if constexpr (N == 0)      asm volatile("s_waitcnt vmcnt(0)" ::: "memory");
  else if constexpr (N == 3) asm volatile("s_waitcnt vmcnt(3)" ::: "memory");
  else if constexpr (N == 4) asm volatile("s_waitcnt vmcnt(4)" ::: "memory");
  else static_assert(N == 0, "unsupported vmcnt literal");
}

// raw workgroup barrier (no vmcnt(0) drain)
__device__ __forceinline__ void block_sync() {
  asm volatile("" ::: "memory");
  __builtin_amdgcn_s_barrier();
  asm volatile("" ::: "memory");
}

// LDS-visibility barrier: drains lgkmcnt but leaves vmcnt (prefetch) in flight.
__device__ __forceinline__ void lds_sync() {
  asm volatile("s_waitcnt lgkmcnt(0)" ::: "memory");
  __builtin_amdgcn_s_barrier();
  __builtin_amdgcn_sched_barrier(0);
}

// ---------------------------------------------------------------------------
// Stage a ROWS x 32 u16 K-tile with SOURCE-side XOR swizzle (rule #21).
// ---------------------------------------------------------------------------
template <int ROWS>
__device__ __forceinline__ void stage32(const u16* g, int ldk, u16* lds, int t) {
#pragma unroll
  for (int i = 0; i < ROWS / 128; ++i) {
    const int s   = i * 512 + t;
    const int row = s >> 2;
    const int gc  = (s & 3) ^ ((s >> 3) & 3);
    gl_lds16(g + (size_t)row * ldk + gc * 8,
             lds + (size_t)(i * 512 + (t & ~63)) * 8);
  }
}

template <int NF>
__device__ __forceinline__ void compute_tile32(
    const u16* pA, const u16* pB, f32x4 (&acc)[8][NF],
    int wm, int wn, int lm, int cq)
{
  f16x8 bf[NF];
#pragma unroll
  for (int nf = 0; nf < NF; ++nf)
    bf[nf] = *(const f16x8*)(pB + (wn + nf * 16 + lm) * 32 + cq * 8);
#pragma unroll
  for (int mf = 0; mf < 8; ++mf) {
    f16x8 a0 = *(const f16x8*)(pA + (wm + mf * 16 + lm) * 32 + cq * 8);
#pragma unroll
    for (int nf = 0; nf < NF; ++nf)
      acc[mf][nf] = __builtin_amdgcn_mfma_f32_16x16x32_f16(a0, bf[nf], acc[mf][nf], 0, 0, 0);
  }
}

// ---------------------------------------------------------------------------
// bt-GEMM (K1/K2), 256 x BN tile, BK=32, 4-buffer counted-vmcnt pipeline.
// Requires M%256==0, Ncols%BN==0, K%128==0. MODE 0: fp16 out (+bias).
// ---------------------------------------------------------------------------
template <int BN, int MODE>
__global__ __launch_bounds__(512, 2) void gemm32(
    const u16* __restrict__ A, const u16* __restrict__ Bt,
    void* __restrict__ Cv, const float* __restrict__ bias,
    int M, int Ncols, int K,
    long long strideA, long long strideB, long long strideC)
{
  constexpr int NF  = BN / 64;
  constexpr int LPT = 2 + BN / 128;

  __shared__ __align__(16) u16 sA0[256 * 32];
  __shared__ __align__(16) u16 sA1[256 * 32];
  __shared__ __align__(16) u16 sA2[256 * 32];
  __shared__ __align__(16) u16 sA3[256 * 32];
  __shared__ __align__(16) u16 sB0[BN * 32];
  __shared__ __align__(16) u16 sB1[BN * 32];
  __shared__ __align__(16) u16 sB2[BN * 32];
  __shared__ __align__(16) u16 sB3[BN * 32];

  const int bz = blockIdx.z;
  A  += (size_t)bz * strideA;
  Bt += (size_t)bz * strideB;

  const int m0 = blockIdx.y * 256;
  const int n0 = blockIdx.x * BN;
  const int t    = threadIdx.x;
  const int lane = t & 63;
  const int wave = t >> 6;
  const int wm   = (wave >> 2) * 128;
  const int wn   = (wave & 3) * (BN / 4);
  const int lm   = lane & 15;
  const int quad = lane >> 4;
  const int cq   = quad ^ ((lm >> 1) & 3);

  f32x4 acc[8][NF];
#pragma unroll
  for (int i = 0; i < 8; ++i)
#pragma unroll
    for (int j = 0; j < NF; ++j) acc[i][j] = f32x4{0.f, 0.f, 0.f, 0.f};

  const u16* Ag = A + (size_t)m0 * K;
  const u16* Bg = Bt + (size_t)n0 * K;

  const int nk = K >> 5;

  stage32<256>(Ag,      K, sA0, t);  stage32<BN>(Bg,      K, sB0, t);
  stage32<256>(Ag + 32, K, sA1, t);  stage32<BN>(Bg + 32, K, sB1, t);

  for (int kt = 0; kt < nk - 4; kt += 4) {
    vmcnt_wait<LPT>(); block_sync();
    stage32<256>(Ag + (size_t)(kt + 2) * 32, K, sA2, t);
    stage32<BN >(Bg + (size_t)(kt + 2) * 32, K, sB2, t);
    compute_tile32<NF>(sA0, sB0, acc, wm, wn, lm, cq);

    vmcnt_wait<LPT>(); block_sync();
    stage32<256>(Ag + (size_t)(kt + 3) * 32, K, sA3, t);
    stage32<BN >(Bg + (size_t)(kt + 3) * 32, K, sB3, t);
    compute_tile32<NF>(sA1, sB1, acc, wm, wn, lm, cq);

    vmcnt_wait<LPT>(); block_sync();
    stage32<256>(Ag + (size_t)(kt + 4) * 32, K, sA0, t);
    stage32<BN >(Bg + (size_t)(kt + 4) * 32, K, sB0, t);
    compute_tile32<NF>(sA2, sB2, acc, wm, wn, lm, cq);

    vmcnt_wait<LPT>(); block_sync();
    stage32<256>(Ag + (size_t)(kt + 5) * 32, K, sA1, t);
    stage32<BN >(Bg + (size_t)(kt + 5) * 32, K, sB1, t);
    compute_tile32<NF>(sA3, sB3, acc, wm, wn, lm, cq);
  }

  vmcnt_wait<LPT>(); block_sync();
  stage32<256>(Ag + (size_t)(nk - 2) * 32, K, sA2, t);
  stage32<BN >(Bg + (size_t)(nk - 2) * 32, K, sB2, t);
  compute_tile32<NF>(sA0, sB0, acc, wm, wn, lm, cq);

  vmcnt_wait<LPT>(); block_sync();
  stage32<256>(Ag + (size_t)(nk - 1) * 32, K, sA3, t);
  stage32<BN >(Bg + (size_t)(nk - 1) * 32, K, sB3, t);
  compute_tile32<NF>(sA1, sB1, acc, wm, wn, lm, cq);

  vmcnt_wait<LPT>(); block_sync();
  compute_tile32<NF>(sA2, sB2, acc, wm, wn, lm, cq);

  vmcnt_wait<0>(); block_sync();
  compute_tile32<NF>(sA3, sB3, acc, wm, wn, lm, cq);

  if (MODE == 0) {
    u16* C = (u16*)Cv + (size_t)bz * strideC;
#pragma unroll
    for (int nf = 0; nf < NF; ++nf) {
      const int col = n0 + wn + nf * 16 + lm;
      const float bv = bias ? bias[col] : 0.f;
#pragma unroll
      for (int mf = 0; mf < 8; ++mf)
#pragma unroll
        for (int r = 0; r < 4; ++r) {
          const int row = m0 + wm + mf * 16 + quad * 4 + r;
          C[(size_t)row * Ncols + col] = f2h(acc[mf][nf][r] + bv);
        }
    }
  } else {
    float* C = (float*)Cv + (size_t)bz * strideC;
#pragma unroll
    for (int nf = 0; nf < NF; ++nf) {
      const int col = n0 + wn + nf * 16 + lm;
#pragma unroll
      for (int mf = 0; mf < 8; ++mf)
#pragma unroll
        for (int r = 0; r < 4; ++r) {
          const int row = m0 + wm + mf * 16 + quad * 4 + r;
          C[(size_t)row * Ncols + col] = acc[mf][nf][r];
        }
    }
  }
}

// ---------------------------------------------------------------------------
// fused attention helpers — FREE FUNCTIONS (no lambdas: round-5's lambda
// captures forced qreg/o_acc to scratch; WRITE_SIZE +28MB / FETCH +246MB).
// ---------------------------------------------------------------------------

// K-tile stager: [64][512] u16, source chunk pre-swizzled gc = c ^ (row&7)
__device__ __forceinline__ void fa_stageK(const u16* __restrict__ Kb, int kv,
                                          u16* __restrict__ lds, int t) {
#pragma unroll
  for (int i = 0; i < 8; ++i) {
    const int s = i * 512 + t;
    const int row = s >> 6, c = s & 63;
    gl_lds16(Kb + (size_t)(kv + row) * 512 + (size_t)((c ^ (row & 7)) * 8),
             lds + (size_t)(i * 512 + (t & ~63)) * 8);
  }
}

// One kv-tile: compute from curK, prefetch tile T+1 into nxtK.
// Issue order: adj, V-frags, stage(next) — in-order vmcnt retirement keeps the
// stage in flight across the compiler's adj/vf waits; end __syncthreads drains it.
__device__ __forceinline__ void fa_tile(
    const u16* __restrict__ curK, u16* __restrict__ nxtK, int T,
    const u16* __restrict__ Kb, const u16* __restrict__ Vb,
    const int* __restrict__ Ab,
    u16* __restrict__ sP, float* __restrict__ sf,
    float (* __restrict__ pmx)[64], float (* __restrict__ psm)[64],
    const f16x8 (&qreg)[16], float (&m_reg)[4], float (&l_reg)[4],
    f32x4 (&o_acc)[4][4],
    int t, int wave, int lm, int quad, int qf, int kh, int kf0)
{
  constexpr int N = 2048;
  const int kv = T * 64;

  // --- top: issue memory; consumed mid/late so latency hides ---
  int am[2][4];
#pragma unroll
  for (int j = 0; j < 2; ++j)
#pragma unroll
    for (int r = 0; r < 4; ++r)
      am[j][r] = Ab[(size_t)(qf * 16 + quad * 4 + r) * N + kv + (kf0 + j) * 16 + lm];
  f16x8 vf[4][2];
#pragma unroll
  for (int df = 0; df < 4; ++df)
#pragma unroll
    for (int ks = 0; ks < 2; ++ks)
      vf[df][ks] = *(const f16x8*)(Vb + (size_t)(wave * 64 + df * 16 + lm) * N
                                      + kv + ks * 32 + quad * 8);
  if (T + 1 < 32) fa_stageK(Kb, kv + 64, nxtK, t);  // drains at end __syncthreads

  // --- QK ---
  f32x4 sfr[2];
  sfr[0] = f32x4{0.f, 0.f, 0.f, 0.f};
  sfr[1] = f32x4{0.f, 0.f, 0.f, 0.f};
  __builtin_amdgcn_s_setprio(1);
#pragma unroll
  for (int j = 0; j < 2; ++j) {
    const int krow = (kf0 + j) * 16 + lm;
#pragma unroll
    for (int s = 0; s < 16; ++s) {
      f16x8 kfr = *(const f16x8*)(curK + (size_t)krow * 512
                                      + (size_t)((((s * 4 + quad) ^ (lm & 7)) * 8)));
      sfr[j] = __builtin_amdgcn_mfma_f32_16x16x32_f16(qreg[s], kfr, sfr[j], 0, 0, 0);
    }
  }
  __builtin_amdgcn_s_setprio(0);

  // --- mask + partial max (16-lane shfl over lm) ---
  float vmax[4];
#pragma unroll
  for (int r = 0; r < 4; ++r) {
    sfr[0][r] = am[0][r] ? sfr[0][r] : -1e30f;
    sfr[1][r] = am[1][r] ? sfr[1][r] : -1e30f;
    vmax[r] = fmaxf(sfr[0][r], sfr[1][r]);
  }
#pragma unroll
  for (int r = 0; r < 4; ++r)
#pragma unroll
    for (int o = 1; o < 16; o <<= 1) vmax[r] = fmaxf(vmax[r], __shfl_xor(vmax[r], o));
  if (lm == 0)
#pragma unroll
    for (int r = 0; r < 4; ++r) pmx[kh][qf * 16 + quad * 4 + r] = vmax[r];
  lds_sync();  // B1: pmx visible; prefetch stays in flight

  // --- m/f update (redundant per wave-pair); P + partial sums ---
  float f_[4], vsum[4];
#pragma unroll
  for (int r = 0; r < 4; ++r) {
    const int row = qf * 16 + quad * 4 + r;
    const float mn = fmaxf(m_reg[r], fmaxf(pmx[0][row], pmx[1][row]));
    f_[r] = __expf(m_reg[r] - mn);
    m_reg[r] = mn;
    const float e0 = __expf(sfr[0][r] - mn);
    const float e1 = __expf(sfr[1][r] - mn);
    vsum[r] = e0 + e1;
    const int rq = row & 7;
    sP[(size_t)row * 64 + (size_t)((((kf0    ) * 2 + (lm >> 3)) ^ rq) * 8) + (lm & 7)] = f2h(e0);
    sP[(size_t)row * 64 + (size_t)((((kf0 + 1) * 2 + (lm >> 3)) ^ rq) * 8) + (lm & 7)] = f2h(e1);
  }
#pragma unroll
  for (int r = 0; r < 4; ++r)
#pragma unroll
    for (int o = 1; o < 16; o <<= 1) vsum[r] += __shfl_xor(vsum[r], o);
  if (lm == 0)
#pragma unroll
    for (int r = 0; r < 4; ++r) psm[kh][qf * 16 + quad * 4 + r] = vsum[r];
  if (kh == 0 && lm == 0)
#pragma unroll
    for (int r = 0; r < 4; ++r) sf[qf * 16 + quad * 4 + r] = f_[r];
  lds_sync();  // B2: sP/sf/psm visible

  // l update (redundant in pair)
#pragma unroll
  for (int r = 0; r < 4; ++r) {
    const int row = qf * 16 + quad * 4 + r;
    l_reg[r] = l_reg[r] * f_[r] + psm[0][row] + psm[1][row];
  }

  // --- PV: rescale O, accumulate P.V ---
#pragma unroll
  for (int qi = 0; qi < 4; ++qi) {
    float fr[4];
#pragma unroll
    for (int r = 0; r < 4; ++r) fr[r] = sf[qi * 16 + quad * 4 + r];
#pragma unroll
    for (int df = 0; df < 4; ++df)
#pragma unroll
      for (int r = 0; r < 4; ++r) o_acc[qi][df][r] *= fr[r];
    __builtin_amdgcn_s_setprio(1);
#pragma unroll
    for (int ks = 0; ks < 2; ++ks) {
      const int prow = qi * 16 + lm;
      f16x8 pa = *(const f16x8*)(sP + (size_t)prow * 64
                                    + (size_t)((((ks * 4 + quad) ^ (lm & 7)) * 8)));
#pragma unroll
      for (int df = 0; df < 4; ++df)
        o_acc[qi][df] = __builtin_amdgcn_mfma_f32_16x16x32_f16(pa, vf[df][ks], o_acc[qi][df], 0, 0, 0);
    }
    __builtin_amdgcn_s_setprio(0);
  }
  __syncthreads();  // B3: full drain — prefetch landed, sP reads done
}

// ---------------------------------------------------------------------------
// Fused K3+softmax+K5 v3: round-5 dbuf schedule with lambda-free codegen.
// Per batch bz, 64 Q-rows per block. 8 waves: QK wave w -> (qf=w>>1, kh=w&1);
// PV wave w -> d-cols w*64..+63.
// ---------------------------------------------------------------------------
__global__ __launch_bounds__(512, 2) void fused_attn(
    const u16* __restrict__ Qg, const u16* __restrict__ Kg,
    const u16* __restrict__ Vt, const int* __restrict__ adj,
    float* __restrict__ out)
{
  constexpr int N = 2048, D = 512;
  __shared__ __align__(16) u16 sK0[64 * 512];  // 64 KB
  __shared__ __align__(16) u16 sK1[64 * 512];  // 64 KB
  __shared__ __align__(16) u16 sP[64 * 64];    // 8 KB
  __shared__ float sf[64], sl[64];
  __shared__ float pmx[2][64], psm[2][64];

  const int bz = blockIdx.y;
  const int q0 = blockIdx.x * 64;
  const u16* Qb = Qg + ((size_t)bz * N + q0) * D;
  const u16* Kb = Kg + (size_t)bz * N * D;
  const u16* Vb = Vt + (size_t)bz * D * N;
  const int* Ab = adj + ((size_t)bz * N + q0) * N;
  float*     Ob = out + ((size_t)bz * N + q0) * D;

  const int t = threadIdx.x;
  const int lane = t & 63, wave = t >> 6;
  const int lm = lane & 15, quad = lane >> 4;
  const int qf  = wave >> 1;
  const int kh  = wave & 1;
  const int kf0 = kh * 2;

  // Q cache: A-frag layout (row = lane&15, k = quad*8+e), 16 d-steps of 32.
  f16x8 qreg[16];
#pragma unroll
  for (int s = 0; s < 16; ++s)
    qreg[s] = *(const f16x8*)(Qb + (size_t)(qf * 16 + lm) * D + s * 32 + quad * 8);

  float m_reg[4], l_reg[4];
#pragma unroll
  for (int r = 0; r < 4; ++r) { m_reg[r] = -1e30f; l_reg[r] = 0.f; }

  f32x4 o_acc[4][4];
#pragma unroll
  for (int i = 0; i < 4; ++i)
#pragma unroll
    for (int j = 0; j < 4; ++j) o_acc[i][j] = f32x4{0.f, 0.f, 0.f, 0.f};

  fa_stageK(Kb, 0, sK0, t);
  __syncthreads();  // prologue: tile 0 staged

  for (int kt = 0; kt < 32; kt += 2) {
    fa_tile(sK0, sK1, kt,     Kb, Vb, Ab, sP, sf, pmx, psm,
            qreg, m_reg, l_reg, o_acc, t, wave, lm, quad, qf, kh, kf0);
    fa_tile(sK1, sK0, kt + 1, Kb, Vb, Ab, sP, sf, pmx, psm,
            qreg, m_reg, l_reg, o_acc, t, wave, lm, quad, qf, kh, kf0);
  }

  // publish l (pair computed redundantly; kh==0 writes)
  if (kh == 0 && lm == 0)
#pragma unroll
    for (int r = 0; r < 4; ++r) sl[qf * 16 + quad * 4 + r] = l_reg[r];
  __syncthreads();

  // epilogue: out = elu(O / l)
#pragma unroll
  for (int qi = 0; qi < 4; ++qi) {
    float il[4];
#pragma unroll
    for (int r = 0; r < 4; ++r) il[r] = 1.f / sl[qi * 16 + quad * 4 + r];
#pragma unroll
    for (int df = 0; df < 4; ++df)
#pragma unroll
      for (int r = 0; r < 4; ++r) {
        float v = o_acc[qi][df][r] * il[r];
        v = v > 0.f ? v : expm1f(v);
        Ob[(size_t)(qi * 16 + quad * 4 + r) * D + wave * 64 + df * 16 + lm] = v;
      }
  }
}

// ---------------------------------------------------------------------------
// 16-bit transpose per batch (z): in [R][C] -> out [C][R], 64x64 LDS tiles
// ---------------------------------------------------------------------------
__global__ __launch_bounds__(256) void transpose_u16(
    const u16* __restrict__ in, u16* __restrict__ outp, int R, int C)
{
  __shared__ u16 tile[64][65];
  const size_t base = (size_t)blockIdx.z * R * C;
  const int r0 = blockIdx.y * 64, c0 = blockIdx.x * 64;
  const int t = threadIdx.x;
  const int c = t & 63, rr = t >> 6;
#pragma unroll
  for (int i = 0; i < 16; ++i) {
    const int r = rr + i * 4;
    tile[r][c] = in[base + (size_t)(r0 + r) * C + c0 + c];
  }
  __syncthreads();
  const int rp = t & 63, cc = t >> 6;
#pragma unroll
  for (int i = 0; i < 16; ++i) {
    const int cq2 = cc + i * 4;
    outp[base + (size_t)(c0 + cq2) * R + r0 + rp] = tile[rp][cq2];
  }
}

__global__ __launch_bounds__(256) void cvt_f32_f16(
    const float* __restrict__ in, u16* __restrict__ outp, int n4)
{
  const int i = blockIdx.x * 256 + threadIdx.x;
  if (i >= n4) return;
  float4 v = ((const float4*)in)[i];
  u16x4 o; o[0] = f2h(v.x); o[1] = f2h(v.y); o[2] = f2h(v.z); o[3] = f2h(v.w);
  ((u16x4*)outp)[i] = o;
}

// out[j*R + i] = fp16(in[i*C + j])  (coalesced reads, tiny matrix)
__global__ __launch_bounds__(256) void transpose_cvt(
    const float* __restrict__ in, u16* __restrict__ outp, int R, int C)
{
  const int idx = blockIdx.x * 256 + threadIdx.x;
  const int i = idx / C, j = idx % C;
  outp[(size_t)j * R + i] = f2h(in[idx]);
}

// ---------------------------------------------------------------------------
extern "C" void kernel_launch(void* const* d_in, const int* in_sizes, int n_in,
                              void* d_out, int out_size, void* d_ws, size_t ws_size,
                              hipStream_t stream) {
  (void)in_sizes; (void)n_in; (void)out_size;
  const float* x    = (const float*)d_in[0];
  const int*   adj  = (const int*)d_in[1];
  const float* W    = (const float*)d_in[2];
  const float* bvec = (const float*)d_in[3];
  const float* attn = (const float*)d_in[4];
  float* out = (float*)d_out;

  constexpr int B = 8, N = 2048, D = 512;
  constexpr size_t MN = (size_t)B * N;  // 16384

  char* ws = (char*)d_ws;
  size_t off = 0;
  auto take = [&](size_t bytes) -> char* {
    char* p = ws + off;
    off += (bytes + 255) & ~(size_t)255;
    return p;
  };
  u16* xh   = (u16*)take(MN * D * 2);
  u16* Wh   = (u16*)take((size_t)D * D * 2);
  u16* attT = (u16*)take((size_t)D * D * 2);
  u16* h    = (u16*)take(MN * D * 2);
  u16* hT   = (u16*)take(MN * D * 2);
  u16* ha   = (u16*)take(MN * D * 2);
  if (ws_size < off) return;  // ws too small; fail validation cleanly

  // converts
  cvt_f32_f16<<<dim3((unsigned)(MN * D / 4 / 256)), 256, 0, stream>>>(x, xh, (int)(MN * D / 4));
  cvt_f32_f16<<<dim3(D * D / 4 / 256), 256, 0, stream>>>(W, Wh, D * D / 4);
  transpose_cvt<<<dim3(D * D / 256), 256, 0, stream>>>(attn, attT, D, D);

  // K1: h = xh . Wh^T + bias   [16384,512] x [512,512]
  gemm32<128, 0><<<dim3(D / 128, MN / 256, 1), 512, 0, stream>>>(
      xh, Wh, h, bvec, (int)MN, D, D, 0, 0, 0);
  // hT per batch: [2048,512] -> [512,2048]
  transpose_u16<<<dim3(D / 64, N / 64, B), 256, 0, stream>>>(h, hT, N, D);
  // K2: ha = h . attT^T
  gemm32<128, 0><<<dim3(D / 128, MN / 256, 1), 512, 0, stream>>>(
      h, attT, ha, nullptr, (int)MN, D, D, 0, 0, 0);

  // fused K3 + masked softmax + K5 (+ELU): 256 blocks, 1/CU
  fused_attn<<<dim3(N / 64, B), 512, 0, stream>>>(ha, h, hT, adj, out);
}

// Round 7
// 537.620 us; speedup vs baseline: 1.3200x; 1.3200x over previous
//
#include <hip/hip_runtime.h>
#include <cstdint>
#include <cstddef>

typedef unsigned short u16;
using f16x8 = __attribute__((ext_vector_type(8))) _Float16;
using f32x4 = __attribute__((ext_vector_type(4))) float;
using u16x4 = __attribute__((ext_vector_type(4))) unsigned short;

// float -> fp16 bit pattern (round-to-nearest-even via v_cvt_f16_f32)
__device__ __forceinline__ u16 f2h(float f) {
  union { _Float16 h; u16 u; } c;
  c.h = (_Float16)f;
  return c.u;
}

// async global->LDS, 16B per lane. LDS dest must be wave-uniform base; HW writes base + lane*16.
__device__ __forceinline__ void gl_lds16(const void* g, void* lds) {
  __builtin_amdgcn_global_load_lds(
      (const __attribute__((address_space(1))) void*)(uintptr_t)g,
      (__attribute__((address_space(3))) void*)(uint32_t)(uintptr_t)lds,
      16, 0, 0);
}

// counted vmcnt wait (inline asm, literal immediate)
template <int N> __device__ __forceinline__ void vmcnt_wait() {
  if constexpr (N == 0)      asm volatile("s_waitcnt vmcnt(0)" ::: "memory");
  else if constexpr (N == 3) asm volatile("s_waitcnt vmcnt(3)" ::: "memory");
  else if constexpr (N == 4) asm volatile("s_waitcnt vmcnt(4)" ::: "memory");
  else static_assert(N == 0, "unsupported vmcnt literal");
}

// raw workgroup barrier (no vmcnt(0) drain)
__device__ __forceinline__ void block_sync() {
  asm volatile("" ::: "memory");
  __builtin_amdgcn_s_barrier();
  asm volatile("" ::: "memory");
}

// ---------------------------------------------------------------------------
// Stage a ROWS x 32 u16 K-tile with SOURCE-side XOR swizzle (rule #21).
// ---------------------------------------------------------------------------
template <int ROWS>
__device__ __forceinline__ void stage32(const u16* g, int ldk, u16* lds, int t) {
#pragma unroll
  for (int i = 0; i < ROWS / 128; ++i) {
    const int s   = i * 512 + t;
    const int row = s >> 2;
    const int gc  = (s & 3) ^ ((s >> 3) & 3);
    gl_lds16(g + (size_t)row * ldk + gc * 8,
             lds + (size_t)(i * 512 + (t & ~63)) * 8);
  }
}

template <int NF>
__device__ __forceinline__ void compute_tile32(
    const u16* pA, const u16* pB, f32x4 (&acc)[8][NF],
    int wm, int wn, int lm, int cq)
{
  f16x8 bf[NF];
#pragma unroll
  for (int nf = 0; nf < NF; ++nf)
    bf[nf] = *(const f16x8*)(pB + (wn + nf * 16 + lm) * 32 + cq * 8);
#pragma unroll
  for (int mf = 0; mf < 8; ++mf) {
    f16x8 a0 = *(const f16x8*)(pA + (wm + mf * 16 + lm) * 32 + cq * 8);
#pragma unroll
    for (int nf = 0; nf < NF; ++nf)
      acc[mf][nf] = __builtin_amdgcn_mfma_f32_16x16x32_f16(a0, bf[nf], acc[mf][nf], 0, 0, 0);
  }
}

// ---------------------------------------------------------------------------
// bt-GEMM, 256 x BN tile, BK=32, 4-buffer counted-vmcnt pipeline (round-3
// validated). Requires M%256==0, Ncols%BN==0, K%128==0.
// MODE 0: fp16 out (+bias). MODE 1: fp32 out.
// ---------------------------------------------------------------------------
template <int BN, int MODE>
__global__ __launch_bounds__(512, 2) void gemm32(
    const u16* __restrict__ A, const u16* __restrict__ Bt,
    void* __restrict__ Cv, const float* __restrict__ bias,
    int M, int Ncols, int K,
    long long strideA, long long strideB, long long strideC)
{
  constexpr int NF  = BN / 64;
  constexpr int LPT = 2 + BN / 128;

  __shared__ __align__(16) u16 sA0[256 * 32];
  __shared__ __align__(16) u16 sA1[256 * 32];
  __shared__ __align__(16) u16 sA2[256 * 32];
  __shared__ __align__(16) u16 sA3[256 * 32];
  __shared__ __align__(16) u16 sB0[BN * 32];
  __shared__ __align__(16) u16 sB1[BN * 32];
  __shared__ __align__(16) u16 sB2[BN * 32];
  __shared__ __align__(16) u16 sB3[BN * 32];

  const int bz = blockIdx.z;
  A  += (size_t)bz * strideA;
  Bt += (size_t)bz * strideB;

  const int m0 = blockIdx.y * 256;
  const int n0 = blockIdx.x * BN;
  const int t    = threadIdx.x;
  const int lane = t & 63;
  const int wave = t >> 6;
  const int wm   = (wave >> 2) * 128;
  const int wn   = (wave & 3) * (BN / 4);
  const int lm   = lane & 15;
  const int quad = lane >> 4;
  const int cq   = quad ^ ((lm >> 1) & 3);

  f32x4 acc[8][NF];
#pragma unroll
  for (int i = 0; i < 8; ++i)
#pragma unroll
    for (int j = 0; j < NF; ++j) acc[i][j] = f32x4{0.f, 0.f, 0.f, 0.f};

  const u16* Ag = A + (size_t)m0 * K;
  const u16* Bg = Bt + (size_t)n0 * K;

  const int nk = K >> 5;

  stage32<256>(Ag,      K, sA0, t);  stage32<BN>(Bg,      K, sB0, t);
  stage32<256>(Ag + 32, K, sA1, t);  stage32<BN>(Bg + 32, K, sB1, t);

  for (int kt = 0; kt < nk - 4; kt += 4) {
    vmcnt_wait<LPT>(); block_sync();
    stage32<256>(Ag + (size_t)(kt + 2) * 32, K, sA2, t);
    stage32<BN >(Bg + (size_t)(kt + 2) * 32, K, sB2, t);
    compute_tile32<NF>(sA0, sB0, acc, wm, wn, lm, cq);

    vmcnt_wait<LPT>(); block_sync();
    stage32<256>(Ag + (size_t)(kt + 3) * 32, K, sA3, t);
    stage32<BN >(Bg + (size_t)(kt + 3) * 32, K, sB3, t);
    compute_tile32<NF>(sA1, sB1, acc, wm, wn, lm, cq);

    vmcnt_wait<LPT>(); block_sync();
    stage32<256>(Ag + (size_t)(kt + 4) * 32, K, sA0, t);
    stage32<BN >(Bg + (size_t)(kt + 4) * 32, K, sB0, t);
    compute_tile32<NF>(sA2, sB2, acc, wm, wn, lm, cq);

    vmcnt_wait<LPT>(); block_sync();
    stage32<256>(Ag + (size_t)(kt + 5) * 32, K, sA1, t);
    stage32<BN >(Bg + (size_t)(kt + 5) * 32, K, sB1, t);
    compute_tile32<NF>(sA3, sB3, acc, wm, wn, lm, cq);
  }

  vmcnt_wait<LPT>(); block_sync();
  stage32<256>(Ag + (size_t)(nk - 2) * 32, K, sA2, t);
  stage32<BN >(Bg + (size_t)(nk - 2) * 32, K, sB2, t);
  compute_tile32<NF>(sA0, sB0, acc, wm, wn, lm, cq);

  vmcnt_wait<LPT>(); block_sync();
  stage32<256>(Ag + (size_t)(nk - 1) * 32, K, sA3, t);
  stage32<BN >(Bg + (size_t)(nk - 1) * 32, K, sB3, t);
  compute_tile32<NF>(sA1, sB1, acc, wm, wn, lm, cq);

  vmcnt_wait<LPT>(); block_sync();
  compute_tile32<NF>(sA2, sB2, acc, wm, wn, lm, cq);

  vmcnt_wait<0>(); block_sync();
  compute_tile32<NF>(sA3, sB3, acc, wm, wn, lm, cq);

  if (MODE == 0) {
    u16* C = (u16*)Cv + (size_t)bz * strideC;
#pragma unroll
    for (int nf = 0; nf < NF; ++nf) {
      const int col = n0 + wn + nf * 16 + lm;
      const float bv = bias ? bias[col] : 0.f;
#pragma unroll
      for (int mf = 0; mf < 8; ++mf)
#pragma unroll
        for (int r = 0; r < 4; ++r) {
          const int row = m0 + wm + mf * 16 + quad * 4 + r;
          C[(size_t)row * Ncols + col] = f2h(acc[mf][nf][r] + bv);
        }
    }
  } else {
    float* C = (float*)Cv + (size_t)bz * strideC;
#pragma unroll
    for (int nf = 0; nf < NF; ++nf) {
      const int col = n0 + wn + nf * 16 + lm;
#pragma unroll
      for (int mf = 0; mf < 8; ++mf)
#pragma unroll
        for (int r = 0; r < 4; ++r) {
          const int row = m0 + wm + mf * 16 + quad * 4 + r;
          C[(size_t)row * Ncols + col] = acc[mf][nf][r];
        }
    }
  }
}

// ---------------------------------------------------------------------------
// smpv: fused masked-softmax + PV + ELU.  out = elu(softmax(mask(S)) . h)
// S precomputed by K3 (fp32, L3-resident). Per block: 32 Q-rows of batch bz;
// 512 threads / 8 waves; grid 512 blocks = 2 blocks/CU (TLP hides streaming).
// Softmax roles: wave = qf*4+kf handles S-frag (qf 16 rows, kf 16 cols);
// PV roles: wave owns d-cols wave*64..+63; V-frags direct from L2 (hT).
// Online max/exp math identical to the round-4-validated fused kernel.
// Parity double-buffered sP/pmx/psm/sf -> 2 barriers per kv-tile, no B3
// (>=2 barriers separate read(T) from same-parity write(T+2)).
// Per-thread persistent state: o_acc 32 VGPR only (no Q cache -> no spill).
// ---------------------------------------------------------------------------
__global__ __launch_bounds__(512, 4) void smpv(
    const float* __restrict__ S, const int* __restrict__ adj,
    const u16* __restrict__ Vt, float* __restrict__ out)
{
  constexpr int N = 2048, D = 512;
  __shared__ __align__(16) u16 sP[2][32 * 64];   // swizzled P, fp16
  __shared__ float sf[2][32];                    // per-row rescale factor
  __shared__ float pmx[2][4][32], psm[2][4][32]; // per-kf partial max/sum
  __shared__ float sl[32];

  const int bz = blockIdx.y;
  const int q0 = blockIdx.x * 32;
  const float* Sb = S   + ((size_t)bz * N + q0) * N;
  const int*   Ab = adj + ((size_t)bz * N + q0) * N;
  const u16*   Vb = Vt  + (size_t)bz * D * N;
  float*       Ob = out + ((size_t)bz * N + q0) * D;

  const int t = threadIdx.x;
  const int lane = t & 63, wave = t >> 6;
  const int lm = lane & 15, quad = lane >> 4;
  const int qf = wave >> 2;   // 0..1: q-frag for softmax role
  const int kf = wave & 3;    // 0..3: k-frag for softmax role

  float m_reg[4], l_reg[4];
#pragma unroll
  for (int r = 0; r < 4; ++r) { m_reg[r] = -1e30f; l_reg[r] = 0.f; }

  f32x4 o_acc[2][4];
#pragma unroll
  for (int i = 0; i < 2; ++i)
#pragma unroll
    for (int j = 0; j < 4; ++j) o_acc[i][j] = f32x4{0.f, 0.f, 0.f, 0.f};

  for (int T = 0; T < 32; ++T) {
    const int kv = T * 64, tp = T & 1;
    const int col = kv + kf * 16 + lm;

    // --- issue all loads up front; consumed mid/late ---
    float sv[4]; int am[4];
#pragma unroll
    for (int r = 0; r < 4; ++r) {
      const int row = qf * 16 + quad * 4 + r;
      sv[r] = Sb[(size_t)row * N + col];
      am[r] = Ab[(size_t)row * N + col];
    }
    f16x8 vf[4][2];
#pragma unroll
    for (int df = 0; df < 4; ++df)
#pragma unroll
      for (int ks = 0; ks < 2; ++ks)
        vf[df][ks] = *(const f16x8*)(Vb + (size_t)(wave * 64 + df * 16 + lm) * N
                                        + kv + ks * 32 + quad * 8);

    // --- mask + 16-lane max reduce ---
    float vmax[4];
#pragma unroll
    for (int r = 0; r < 4; ++r) { sv[r] = am[r] ? sv[r] : -1e30f; vmax[r] = sv[r]; }
#pragma unroll
    for (int r = 0; r < 4; ++r)
#pragma unroll
      for (int o = 1; o < 16; o <<= 1) vmax[r] = fmaxf(vmax[r], __shfl_xor(vmax[r], o));
    if (lm == 0)
#pragma unroll
      for (int r = 0; r < 4; ++r) pmx[tp][kf][qf * 16 + quad * 4 + r] = vmax[r];
    __syncthreads();  // B1: pmx visible

    // --- m/f update (redundant across the 4 kf-waves of a qf); P + sums ---
    float f_[4], vsum[4];
#pragma unroll
    for (int r = 0; r < 4; ++r) {
      const int row = qf * 16 + quad * 4 + r;
      float mn = fmaxf(fmaxf(pmx[tp][0][row], pmx[tp][1][row]),
                       fmaxf(pmx[tp][2][row], pmx[tp][3][row]));
      mn = fmaxf(m_reg[r], mn);
      f_[r] = __expf(m_reg[r] - mn);
      m_reg[r] = mn;
      const float e = __expf(sv[r] - mn);
      vsum[r] = e;
      sP[tp][row * 64 + (((kf * 2 + (lm >> 3)) ^ (row & 7)) * 8) + (lm & 7)] = f2h(e);
    }
#pragma unroll
    for (int r = 0; r < 4; ++r)
#pragma unroll
      for (int o = 1; o < 16; o <<= 1) vsum[r] += __shfl_xor(vsum[r], o);
    if (lm == 0)
#pragma unroll
      for (int r = 0; r < 4; ++r) psm[tp][kf][qf * 16 + quad * 4 + r] = vsum[r];
    if (kf == 0 && lm == 0)
#pragma unroll
      for (int r = 0; r < 4; ++r) sf[tp][qf * 16 + quad * 4 + r] = f_[r];
    __syncthreads();  // B2: sP/psm/sf visible

    // l update (redundant across kf-waves)
#pragma unroll
    for (int r = 0; r < 4; ++r) {
      const int row = qf * 16 + quad * 4 + r;
      l_reg[r] = l_reg[r] * f_[r]
               + psm[tp][0][row] + psm[tp][1][row] + psm[tp][2][row] + psm[tp][3][row];
    }

    // --- PV: rescale O, accumulate P.V ---
#pragma unroll
    for (int qi = 0; qi < 2; ++qi) {
      float fr[4];
#pragma unroll
      for (int r = 0; r < 4; ++r) fr[r] = sf[tp][qi * 16 + quad * 4 + r];
#pragma unroll
      for (int df = 0; df < 4; ++df)
#pragma unroll
        for (int r = 0; r < 4; ++r) o_acc[qi][df][r] *= fr[r];
#pragma unroll
      for (int ks = 0; ks < 2; ++ks) {
        const int prow = qi * 16 + lm;
        f16x8 pa = *(const f16x8*)(sP[tp] + prow * 64
                                    + (((ks * 4 + quad) ^ (prow & 7)) * 8));
#pragma unroll
        for (int df = 0; df < 4; ++df)
          o_acc[qi][df] = __builtin_amdgcn_mfma_f32_16x16x32_f16(pa, vf[df][ks], o_acc[qi][df], 0, 0, 0);
      }
    }
    // no end-of-tile barrier: parity buffers + B1/B2 of the next tile
    // separate these reads from the next same-parity writes.
  }

  if (kf == 0 && lm == 0)
#pragma unroll
    for (int r = 0; r < 4; ++r) sl[qf * 16 + quad * 4 + r] = l_reg[r];
  __syncthreads();

  // epilogue: out = elu(O / l)
#pragma unroll
  for (int qi = 0; qi < 2; ++qi) {
    float il[4];
#pragma unroll
    for (int r = 0; r < 4; ++r) il[r] = 1.f / sl[qi * 16 + quad * 4 + r];
#pragma unroll
    for (int df = 0; df < 4; ++df)
#pragma unroll
      for (int r = 0; r < 4; ++r) {
        float v = o_acc[qi][df][r] * il[r];
        v = v > 0.f ? v : expm1f(v);
        Ob[(size_t)(qi * 16 + quad * 4 + r) * D + wave * 64 + df * 16 + lm] = v;
      }
  }
}

// ---------------------------------------------------------------------------
// 16-bit transpose per batch (z): in [R][C] -> out [C][R], 64x64 LDS tiles
// ---------------------------------------------------------------------------
__global__ __launch_bounds__(256) void transpose_u16(
    const u16* __restrict__ in, u16* __restrict__ outp, int R, int C)
{
  __shared__ u16 tile[64][65];
  const size_t base = (size_t)blockIdx.z * R * C;
  const int r0 = blockIdx.y * 64, c0 = blockIdx.x * 64;
  const int t = threadIdx.x;
  const int c = t & 63, rr = t >> 6;
#pragma unroll
  for (int i = 0; i < 16; ++i) {
    const int r = rr + i * 4;
    tile[r][c] = in[base + (size_t)(r0 + r) * C + c0 + c];
  }
  __syncthreads();
  const int rp = t & 63, cc = t >> 6;
#pragma unroll
  for (int i = 0; i < 16; ++i) {
    const int cq2 = cc + i * 4;
    outp[base + (size_t)(c0 + cq2) * R + r0 + rp] = tile[rp][cq2];
  }
}

__global__ __launch_bounds__(256) void cvt_f32_f16(
    const float* __restrict__ in, u16* __restrict__ outp, int n4)
{
  const int i = blockIdx.x * 256 + threadIdx.x;
  if (i >= n4) return;
  float4 v = ((const float4*)in)[i];
  u16x4 o; o[0] = f2h(v.x); o[1] = f2h(v.y); o[2] = f2h(v.z); o[3] = f2h(v.w);
  ((u16x4*)outp)[i] = o;
}

// out[j*R + i] = fp16(in[i*C + j])  (coalesced reads, tiny matrix)
__global__ __launch_bounds__(256) void transpose_cvt(
    const float* __restrict__ in, u16* __restrict__ outp, int R, int C)
{
  const int idx = blockIdx.x * 256 + threadIdx.x;
  const int i = idx / C, j = idx % C;
  outp[(size_t)j * R + i] = f2h(in[idx]);
}

// ---------------------------------------------------------------------------
extern "C" void kernel_launch(void* const* d_in, const int* in_sizes, int n_in,
                              void* d_out, int out_size, void* d_ws, size_t ws_size,
                              hipStream_t stream) {
  (void)in_sizes; (void)n_in; (void)out_size;
  const float* x    = (const float*)d_in[0];
  const int*   adj  = (const int*)d_in[1];
  const float* W    = (const float*)d_in[2];
  const float* bvec = (const float*)d_in[3];
  const float* attn = (const float*)d_in[4];
  float* out = (float*)d_out;

  constexpr int B = 8, N = 2048, D = 512;
  constexpr size_t MN = (size_t)B * N;  // 16384

  char* ws = (char*)d_ws;
  size_t off = 0;
  auto take = [&](size_t bytes) -> char* {
    char* p = ws + off;
    off += (bytes + 255) & ~(size_t)255;
    return p;
  };
  u16* xh   = (u16*)take(MN * D * 2);
  u16* Wh   = (u16*)take((size_t)D * D * 2);
  u16* attT = (u16*)take((size_t)D * D * 2);
  u16* h    = (u16*)take(MN * D * 2);
  u16* hT   = (u16*)take(MN * D * 2);
  u16* ha   = (u16*)take(MN * D * 2);

  auto al = [](size_t b) { return (b + 255) & ~(size_t)255; };
  const size_t szSf = al((size_t)B * N * N * 4);
  const size_t szSb = al((size_t)N * N * 4);
  const bool full  = ws_size >= off + szSf;
  const bool ok_pb = ws_size >= off + szSb;
  if (!full && !ok_pb) return;  // ws too small; fail validation cleanly

  // converts
  cvt_f32_f16<<<dim3((unsigned)(MN * D / 4 / 256)), 256, 0, stream>>>(x, xh, (int)(MN * D / 4));
  cvt_f32_f16<<<dim3(D * D / 4 / 256), 256, 0, stream>>>(W, Wh, D * D / 4);
  transpose_cvt<<<dim3(D * D / 256), 256, 0, stream>>>(attn, attT, D, D);

  // K1: h = xh . Wh^T + bias   [16384,512] x [512,512]
  gemm32<128, 0><<<dim3(D / 128, MN / 256, 1), 512, 0, stream>>>(
      xh, Wh, h, bvec, (int)MN, D, D, 0, 0, 0);
  // hT per batch: [2048,512] -> [512,2048]
  transpose_u16<<<dim3(D / 64, N / 64, B), 256, 0, stream>>>(h, hT, N, D);
  // K2: ha = h . attT^T
  gemm32<128, 0><<<dim3(D / 128, MN / 256, 1), 512, 0, stream>>>(
      h, attT, ha, nullptr, (int)MN, D, D, 0, 0, 0);

  if (full) {
    float* S = (float*)take(szSf);
    // K3: S = ha . h^T per batch  (256x256 tiles)
    gemm32<256, 1><<<dim3(N / 256, N / 256, B), 512, 0, stream>>>(
        ha, h, S, nullptr, N, N, D,
        (long long)N * D, (long long)N * D, (long long)N * N);
    // fused masked-softmax + PV + ELU: 512 blocks, 2/CU
    smpv<<<dim3(N / 32, B), 512, 0, stream>>>(S, adj, hT, out);
  } else {
    float* S = (float*)take(szSb);
    for (int b = 0; b < B; ++b) {
      gemm32<256, 1><<<dim3(N / 256, N / 256, 1), 512, 0, stream>>>(
          ha + (size_t)b * N * D, h + (size_t)b * N * D, S, nullptr, N, N, D, 0, 0, 0);
      smpv<<<dim3(N / 32, 1), 512, 0, stream>>>(S, adj + (size_t)b * N * N, hT + (size_t)b * D * N,
                                                out + (size_t)b * N * D);
    }
  }
}

// Round 9
// 497.692 us; speedup vs baseline: 1.4259x; 1.0802x over previous
//
#include <hip/hip_runtime.h>
#include <cstdint>
#include <cstddef>

typedef unsigned short u16;
using f16x8 = __attribute__((ext_vector_type(8))) _Float16;
using f32x4 = __attribute__((ext_vector_type(4))) float;
using u16x4 = __attribute__((ext_vector_type(4))) unsigned short;

// float -> fp16 bit pattern (round-to-nearest-even via v_cvt_f16_f32)
__device__ __forceinline__ u16 f2h(float f) {
  union { _Float16 h; u16 u; } c;
  c.h = (_Float16)f;
  return c.u;
}

// async global->LDS, 16B per lane. LDS dest must be wave-uniform base; HW writes base + lane*16.
__device__ __forceinline__ void gl_lds16(const void* g, void* lds) {
  __builtin_amdgcn_global_load_lds(
      (const __attribute__((address_space(1))) void*)(uintptr_t)g,
      (__attribute__((address_space(3))) void*)(uint32_t)(uintptr_t)lds,
      16, 0, 0);
}

// counted vmcnt wait (inline asm, literal immediate)
template <int N> __device__ __forceinline__ void vmcnt_wait() {
  if constexpr (N == 0)      asm volatile("s_waitcnt vmcnt(0)" ::: "memory");
  else if constexpr (N == 3) asm volatile("s_waitcnt vmcnt(3)" ::: "memory");
  else if constexpr (N == 4) asm volatile("s_waitcnt vmcnt(4)" ::: "memory");
  else static_assert(N == 0, "unsupported vmcnt literal");
}

// raw workgroup barrier (no vmcnt(0) drain)
__device__ __forceinline__ void block_sync() {
  asm volatile("" ::: "memory");
  __builtin_amdgcn_s_barrier();
  asm volatile("" ::: "memory");
}

// ---------------------------------------------------------------------------
// Stage a ROWS x 32 u16 K-tile with SOURCE-side XOR swizzle (rule #21).
// ---------------------------------------------------------------------------
template <int ROWS>
__device__ __forceinline__ void stage32(const u16* g, int ldk, u16* lds, int t) {
#pragma unroll
  for (int i = 0; i < ROWS / 128; ++i) {
    const int s   = i * 512 + t;
    const int row = s >> 2;
    const int gc  = (s & 3) ^ ((s >> 3) & 3);
    gl_lds16(g + (size_t)row * ldk + gc * 8,
             lds + (size_t)(i * 512 + (t & ~63)) * 8);
  }
}

template <int NF>
__device__ __forceinline__ void compute_tile32(
    const u16* pA, const u16* pB, f32x4 (&acc)[8][NF],
    int wm, int wn, int lm, int cq)
{
  f16x8 bf[NF];
#pragma unroll
  for (int nf = 0; nf < NF; ++nf)
    bf[nf] = *(const f16x8*)(pB + (wn + nf * 16 + lm) * 32 + cq * 8);
#pragma unroll
  for (int mf = 0; mf < 8; ++mf) {
    f16x8 a0 = *(const f16x8*)(pA + (wm + mf * 16 + lm) * 32 + cq * 8);
#pragma unroll
    for (int nf = 0; nf < NF; ++nf)
      acc[mf][nf] = __builtin_amdgcn_mfma_f32_16x16x32_f16(a0, bf[nf], acc[mf][nf], 0, 0, 0);
  }
}

// ---------------------------------------------------------------------------
// bt-GEMM, 256 x BN tile, BK=32, 4-buffer counted-vmcnt pipeline (round-3
// validated). Requires M%256==0, Ncols%BN==0, K%128==0.
// MODE 0: fp16 out (+bias). MODE 1: fp32 out. MODE 2: fp32 elu out.
// MODE 3: fp32 masked out (C = adj ? v : -1e30) — fuses the adjacency mask.
// ---------------------------------------------------------------------------
template <int BN, int MODE>
__global__ __launch_bounds__(512, 2) void gemm32(
    const u16* __restrict__ A, const u16* __restrict__ Bt,
    void* __restrict__ Cv, const float* __restrict__ bias,
    int M, int Ncols, int K,
    long long strideA, long long strideB, long long strideC,
    const int* __restrict__ adjp, long long strideAdj)
{
  constexpr int NF  = BN / 64;
  constexpr int LPT = 2 + BN / 128;

  __shared__ __align__(16) u16 sA0[256 * 32];
  __shared__ __align__(16) u16 sA1[256 * 32];
  __shared__ __align__(16) u16 sA2[256 * 32];
  __shared__ __align__(16) u16 sA3[256 * 32];
  __shared__ __align__(16) u16 sB0[BN * 32];
  __shared__ __align__(16) u16 sB1[BN * 32];
  __shared__ __align__(16) u16 sB2[BN * 32];
  __shared__ __align__(16) u16 sB3[BN * 32];

  const int bz = blockIdx.z;
  A  += (size_t)bz * strideA;
  Bt += (size_t)bz * strideB;

  const int m0 = blockIdx.y * 256;
  const int n0 = blockIdx.x * BN;
  const int t    = threadIdx.x;
  const int lane = t & 63;
  const int wave = t >> 6;
  const int wm   = (wave >> 2) * 128;
  const int wn   = (wave & 3) * (BN / 4);
  const int lm   = lane & 15;
  const int quad = lane >> 4;
  const int cq   = quad ^ ((lm >> 1) & 3);

  f32x4 acc[8][NF];
#pragma unroll
  for (int i = 0; i < 8; ++i)
#pragma unroll
    for (int j = 0; j < NF; ++j) acc[i][j] = f32x4{0.f, 0.f, 0.f, 0.f};

  const u16* Ag = A + (size_t)m0 * K;
  const u16* Bg = Bt + (size_t)n0 * K;

  const int nk = K >> 5;

  stage32<256>(Ag,      K, sA0, t);  stage32<BN>(Bg,      K, sB0, t);
  stage32<256>(Ag + 32, K, sA1, t);  stage32<BN>(Bg + 32, K, sB1, t);

  for (int kt = 0; kt < nk - 4; kt += 4) {
    vmcnt_wait<LPT>(); block_sync();
    stage32<256>(Ag + (size_t)(kt + 2) * 32, K, sA2, t);
    stage32<BN >(Bg + (size_t)(kt + 2) * 32, K, sB2, t);
    compute_tile32<NF>(sA0, sB0, acc, wm, wn, lm, cq);

    vmcnt_wait<LPT>(); block_sync();
    stage32<256>(Ag + (size_t)(kt + 3) * 32, K, sA3, t);
    stage32<BN >(Bg + (size_t)(kt + 3) * 32, K, sB3, t);
    compute_tile32<NF>(sA1, sB1, acc, wm, wn, lm, cq);

    vmcnt_wait<LPT>(); block_sync();
    stage32<256>(Ag + (size_t)(kt + 4) * 32, K, sA0, t);
    stage32<BN >(Bg + (size_t)(kt + 4) * 32, K, sB0, t);
    compute_tile32<NF>(sA2, sB2, acc, wm, wn, lm, cq);

    vmcnt_wait<LPT>(); block_sync();
    stage32<256>(Ag + (size_t)(kt + 5) * 32, K, sA1, t);
    stage32<BN >(Bg + (size_t)(kt + 5) * 32, K, sB1, t);
    compute_tile32<NF>(sA3, sB3, acc, wm, wn, lm, cq);
  }

  vmcnt_wait<LPT>(); block_sync();
  stage32<256>(Ag + (size_t)(nk - 2) * 32, K, sA2, t);
  stage32<BN >(Bg + (size_t)(nk - 2) * 32, K, sB2, t);
  compute_tile32<NF>(sA0, sB0, acc, wm, wn, lm, cq);

  vmcnt_wait<LPT>(); block_sync();
  stage32<256>(Ag + (size_t)(nk - 1) * 32, K, sA3, t);
  stage32<BN >(Bg + (size_t)(nk - 1) * 32, K, sB3, t);
  compute_tile32<NF>(sA1, sB1, acc, wm, wn, lm, cq);

  vmcnt_wait<LPT>(); block_sync();
  compute_tile32<NF>(sA2, sB2, acc, wm, wn, lm, cq);

  vmcnt_wait<0>(); block_sync();
  compute_tile32<NF>(sA3, sB3, acc, wm, wn, lm, cq);

  if (MODE == 0) {
    u16* C = (u16*)Cv + (size_t)bz * strideC;
#pragma unroll
    for (int nf = 0; nf < NF; ++nf) {
      const int col = n0 + wn + nf * 16 + lm;
      const float bv = bias ? bias[col] : 0.f;
#pragma unroll
      for (int mf = 0; mf < 8; ++mf)
#pragma unroll
        for (int r = 0; r < 4; ++r) {
          const int row = m0 + wm + mf * 16 + quad * 4 + r;
          C[(size_t)row * Ncols + col] = f2h(acc[mf][nf][r] + bv);
        }
    }
  } else if (MODE == 3) {
    float* C = (float*)Cv + (size_t)bz * strideC;
    const int* Az = adjp + (size_t)bz * strideAdj;
#pragma unroll
    for (int nf = 0; nf < NF; ++nf) {
      const int col = n0 + wn + nf * 16 + lm;
#pragma unroll
      for (int mf = 0; mf < 8; ++mf)
#pragma unroll
        for (int r = 0; r < 4; ++r) {
          const int row = m0 + wm + mf * 16 + quad * 4 + r;
          const int am = Az[(size_t)row * Ncols + col];
          C[(size_t)row * Ncols + col] = am ? acc[mf][nf][r] : -1e30f;
        }
    }
  } else {
    float* C = (float*)Cv + (size_t)bz * strideC;
#pragma unroll
    for (int nf = 0; nf < NF; ++nf) {
      const int col = n0 + wn + nf * 16 + lm;
#pragma unroll
      for (int mf = 0; mf < 8; ++mf)
#pragma unroll
        for (int r = 0; r < 4; ++r) {
          const int row = m0 + wm + mf * 16 + quad * 4 + r;
          float v = acc[mf][nf][r];
          if (MODE == 2) v = v > 0.f ? v : expm1f(v);
          C[(size_t)row * Ncols + col] = v;
        }
    }
  }
}

// ---------------------------------------------------------------------------
// softmax over one pre-masked row of 2048 (masked entries are -1e30 in S):
// P = softmax(S), fp16 out. No adj read (mask fused into K3's epilogue).
// ---------------------------------------------------------------------------
__global__ __launch_bounds__(256) void softmax_p(
    const float* __restrict__ S, u16* __restrict__ P)
{
  const size_t row = blockIdx.x;
  const float* s = S + row * 2048;
  u16*         p = P + row * 2048;
  const int t = threadIdx.x;

  float v[8];
#pragma unroll
  for (int i = 0; i < 2; ++i) {
    float4 sv = ((const float4*)s)[t + i * 256];
    v[i * 4 + 0] = sv.x; v[i * 4 + 1] = sv.y;
    v[i * 4 + 2] = sv.z; v[i * 4 + 3] = sv.w;
  }
  float mx = v[0];
#pragma unroll
  for (int i = 1; i < 8; ++i) mx = fmaxf(mx, v[i]);
#pragma unroll
  for (int o = 32; o > 0; o >>= 1) mx = fmaxf(mx, __shfl_xor(mx, o));
  __shared__ float red[4];
  if ((t & 63) == 0) red[t >> 6] = mx;
  __syncthreads();
  mx = fmaxf(fmaxf(red[0], red[1]), fmaxf(red[2], red[3]));
  __syncthreads();

  float e[8]; float sum = 0.f;
#pragma unroll
  for (int i = 0; i < 8; ++i) { e[i] = __expf(v[i] - mx); sum += e[i]; }
#pragma unroll
  for (int o = 32; o > 0; o >>= 1) sum += __shfl_xor(sum, o);
  if ((t & 63) == 0) red[t >> 6] = sum;
  __syncthreads();
  sum = red[0] + red[1] + red[2] + red[3];
  const float inv = 1.f / sum;

#pragma unroll
  for (int i = 0; i < 2; ++i) {
    u16x4 o4;
    o4[0] = f2h(e[i * 4 + 0] * inv);
    o4[1] = f2h(e[i * 4 + 1] * inv);
    o4[2] = f2h(e[i * 4 + 2] * inv);
    o4[3] = f2h(e[i * 4 + 3] * inv);
    ((u16x4*)p)[t + i * 256] = o4;
  }
}

// ---------------------------------------------------------------------------
// 16-bit transpose per batch (z): in [R][C] -> out [C][R], 64x64 LDS tiles
// ---------------------------------------------------------------------------
__global__ __launch_bounds__(256) void transpose_u16(
    const u16* __restrict__ in, u16* __restrict__ outp, int R, int C)
{
  __shared__ u16 tile[64][65];
  const size_t base = (size_t)blockIdx.z * R * C;
  const int r0 = blockIdx.y * 64, c0 = blockIdx.x * 64;
  const int t = threadIdx.x;
  const int c = t & 63, rr = t >> 6;
#pragma unroll
  for (int i = 0; i < 16; ++i) {
    const int r = rr + i * 4;
    tile[r][c] = in[base + (size_t)(r0 + r) * C + c0 + c];
  }
  __syncthreads();
  const int rp = t & 63, cc = t >> 6;
#pragma unroll
  for (int i = 0; i < 16; ++i) {
    const int cq2 = cc + i * 4;
    outp[base + (size_t)(c0 + cq2) * R + r0 + rp] = tile[rp][cq2];
  }
}

__global__ __launch_bounds__(256) void cvt_f32_f16(
    const float* __restrict__ in, u16* __restrict__ outp, int n4)
{
  const int i = blockIdx.x * 256 + threadIdx.x;
  if (i >= n4) return;
  float4 v = ((const float4*)in)[i];
  u16x4 o; o[0] = f2h(v.x); o[1] = f2h(v.y); o[2] = f2h(v.z); o[3] = f2h(v.w);
  ((u16x4*)outp)[i] = o;
}

// out[j*R + i] = fp16(in[i*C + j])  (coalesced reads, tiny matrix)
__global__ __launch_bounds__(256) void transpose_cvt(
    const float* __restrict__ in, u16* __restrict__ outp, int R, int C)
{
  const int idx = blockIdx.x * 256 + threadIdx.x;
  const int i = idx / C, j = idx % C;
  outp[(size_t)j * R + i] = f2h(in[idx]);
}

// ---------------------------------------------------------------------------
extern "C" void kernel_launch(void* const* d_in, const int* in_sizes, int n_in,
                              void* d_out, int out_size, void* d_ws, size_t ws_size,
                              hipStream_t stream) {
  (void)in_sizes; (void)n_in; (void)out_size;
  const float* x    = (const float*)d_in[0];
  const int*   adj  = (const int*)d_in[1];
  const float* W    = (const float*)d_in[2];
  const float* bvec = (const float*)d_in[3];
  const float* attn = (const float*)d_in[4];
  float* out = (float*)d_out;

  constexpr int B = 8, N = 2048, D = 512;
  constexpr size_t MN = (size_t)B * N;  // 16384

  char* ws = (char*)d_ws;
  size_t off = 0;
  auto take = [&](size_t bytes) -> char* {
    char* p = ws + off;
    off += (bytes + 255) & ~(size_t)255;
    return p;
  };
  u16* xh   = (u16*)take(MN * D * 2);
  u16* Wh   = (u16*)take((size_t)D * D * 2);
  u16* attT = (u16*)take((size_t)D * D * 2);
  u16* h    = (u16*)take(MN * D * 2);
  u16* hT   = (u16*)take(MN * D * 2);
  u16* ha   = (u16*)take(MN * D * 2);

  auto al = [](size_t b) { return (b + 255) & ~(size_t)255; };
  const size_t szSf = al((size_t)B * N * N * 4), szPf = al((size_t)B * N * N * 2);
  const size_t szSb = al((size_t)N * N * 4),     szPb = al((size_t)N * N * 2);
  const bool full  = ws_size >= off + szSf + szPf;
  const bool ok_pb = ws_size >= off + szSb + szPb;
  if (!full && !ok_pb) return;  // ws too small; fail validation cleanly

  // converts
  cvt_f32_f16<<<dim3((unsigned)(MN * D / 4 / 256)), 256, 0, stream>>>(x, xh, (int)(MN * D / 4));
  cvt_f32_f16<<<dim3(D * D / 4 / 256), 256, 0, stream>>>(W, Wh, D * D / 4);
  transpose_cvt<<<dim3(D * D / 256), 256, 0, stream>>>(attn, attT, D, D);

  // K1: h = xh . Wh^T + bias   [16384,512] x [512,512]
  gemm32<128, 0><<<dim3(D / 128, MN / 256, 1), 512, 0, stream>>>(
      xh, Wh, h, bvec, (int)MN, D, D, 0, 0, 0, nullptr, 0);
  // hT per batch: [2048,512] -> [512,2048]
  transpose_u16<<<dim3(D / 64, N / 64, B), 256, 0, stream>>>(h, hT, N, D);
  // K2: ha = h . attT^T
  gemm32<128, 0><<<dim3(D / 128, MN / 256, 1), 512, 0, stream>>>(
      h, attT, ha, nullptr, (int)MN, D, D, 0, 0, 0, nullptr, 0);

  if (full) {
    float* S = (float*)take(szSf);
    u16*   P = (u16*)take(szPf);
    // K3: S = mask(ha . h^T) per batch  (256x256 tiles; adj fused in epilogue)
    gemm32<256, 3><<<dim3(N / 256, N / 256, B), 512, 0, stream>>>(
        ha, h, S, nullptr, N, N, D,
        (long long)N * D, (long long)N * D, (long long)N * N,
        adj, (long long)N * N);
    // K4: softmax (S pre-masked) -> P fp16
    softmax_p<<<dim3((unsigned)(B * N)), 256, 0, stream>>>(S, P);
    // K5: out = elu(P . hT^T) per batch
    gemm32<128, 2><<<dim3(D / 128, N / 256, B), 512, 0, stream>>>(
        P, hT, out, nullptr, N, D, N,
        (long long)N * N, (long long)D * N, (long long)N * D, nullptr, 0);
  } else {
    float* S = (float*)take(szSb);
    u16*   P = (u16*)take(szPb);
    for (int b = 0; b < B; ++b) {
      gemm32<256, 3><<<dim3(N / 256, N / 256, 1), 512, 0, stream>>>(
          ha + (size_t)b * N * D, h + (size_t)b * N * D, S, nullptr, N, N, D, 0, 0, 0,
          adj + (size_t)b * N * N, 0);
      softmax_p<<<dim3(N), 256, 0, stream>>>(S, P);
      gemm32<128, 2><<<dim3(D / 128, N / 256, 1), 512, 0, stream>>>(
          P, hT + (size_t)b * D * N, out + (size_t)b * N * D, nullptr, N, D, N, 0, 0, 0,
          nullptr, 0);
    }
  }
}

// Round 10
// 411.835 us; speedup vs baseline: 1.7231x; 1.2085x over previous
//
#include <hip/hip_runtime.h>
#include <cstdint>
#include <cstddef>

typedef unsigned short u16;
using f16x8 = __attribute__((ext_vector_type(8))) _Float16;
using f32x4 = __attribute__((ext_vector_type(4))) float;
using u16x4 = __attribute__((ext_vector_type(4))) unsigned short;

// float -> fp16 bit pattern (round-to-nearest-even via v_cvt_f16_f32)
__device__ __forceinline__ u16 f2h(float f) {
  union { _Float16 h; u16 u; } c;
  c.h = (_Float16)f;
  return c.u;
}

// async global->LDS, 16B per lane. LDS dest must be wave-uniform base; HW writes base + lane*16.
__device__ __forceinline__ void gl_lds16(const void* g, void* lds) {
  __builtin_amdgcn_global_load_lds(
      (const __attribute__((address_space(1))) void*)(uintptr_t)g,
      (__attribute__((address_space(3))) void*)(uint32_t)(uintptr_t)lds,
      16, 0, 0);
}

// counted vmcnt wait (inline asm, literal immediate)
template <int N> __device__ __forceinline__ void vmcnt_wait() {
  if constexpr (N == 0)      asm volatile("s_waitcnt vmcnt(0)" ::: "memory");
  else if constexpr (N == 3) asm volatile("s_waitcnt vmcnt(3)" ::: "memory");
  else if constexpr (N == 4) asm volatile("s_waitcnt vmcnt(4)" ::: "memory");
  else static_assert(N == 0, "unsupported vmcnt literal");
}

// raw workgroup barrier (no vmcnt(0) drain)
__device__ __forceinline__ void block_sync() {
  asm volatile("" ::: "memory");
  __builtin_amdgcn_s_barrier();
  asm volatile("" ::: "memory");
}

// ---------------------------------------------------------------------------
// Stage a ROWS x 32 u16 K-tile with SOURCE-side XOR swizzle (rule #21).
// ---------------------------------------------------------------------------
template <int ROWS>
__device__ __forceinline__ void stage32(const u16* g, int ldk, u16* lds, int t) {
#pragma unroll
  for (int i = 0; i < ROWS / 128; ++i) {
    const int s   = i * 512 + t;
    const int row = s >> 2;
    const int gc  = (s & 3) ^ ((s >> 3) & 3);
    gl_lds16(g + (size_t)row * ldk + gc * 8,
             lds + (size_t)(i * 512 + (t & ~63)) * 8);
  }
}

template <int NF>
__device__ __forceinline__ void compute_tile32(
    const u16* pA, const u16* pB, f32x4 (&acc)[8][NF],
    int wm, int wn, int lm, int cq)
{
  f16x8 bf[NF];
#pragma unroll
  for (int nf = 0; nf < NF; ++nf)
    bf[nf] = *(const f16x8*)(pB + (wn + nf * 16 + lm) * 32 + cq * 8);
#pragma unroll
  for (int mf = 0; mf < 8; ++mf) {
    f16x8 a0 = *(const f16x8*)(pA + (wm + mf * 16 + lm) * 32 + cq * 8);
#pragma unroll
    for (int nf = 0; nf < NF; ++nf)
      acc[mf][nf] = __builtin_amdgcn_mfma_f32_16x16x32_f16(a0, bf[nf], acc[mf][nf], 0, 0, 0);
  }
}

// ---------------------------------------------------------------------------
// bt-GEMM, 256 x BN tile, BK=32, 4-buffer counted-vmcnt pipeline (round-3
// validated). Requires M%256==0, Ncols%BN==0, K%128==0.
// MODE 0: fp16 out (+bias). MODE 1: fp32 out. MODE 2: fp32 elu out.
// SWZ 1: XCD-aware remap (requires gridDim.z==8): lin%8 -> batch, so each
// XCD (round-robin over linear dispatch id) owns exactly one batch's blocks
// -> per-XCD L2 working set = that batch's A+B panels (4MB for K3). Bijective.
// ---------------------------------------------------------------------------
template <int BN, int MODE, int SWZ>
__global__ __launch_bounds__(512, 2) void gemm32(
    const u16* __restrict__ A, const u16* __restrict__ Bt,
    void* __restrict__ Cv, const float* __restrict__ bias,
    int M, int Ncols, int K,
    long long strideA, long long strideB, long long strideC)
{
  constexpr int NF  = BN / 64;
  constexpr int LPT = 2 + BN / 128;

  __shared__ __align__(16) u16 sA0[256 * 32];
  __shared__ __align__(16) u16 sA1[256 * 32];
  __shared__ __align__(16) u16 sA2[256 * 32];
  __shared__ __align__(16) u16 sA3[256 * 32];
  __shared__ __align__(16) u16 sB0[BN * 32];
  __shared__ __align__(16) u16 sB1[BN * 32];
  __shared__ __align__(16) u16 sB2[BN * 32];
  __shared__ __align__(16) u16 sB3[BN * 32];

  int bx = blockIdx.x, by = blockIdx.y, bz = blockIdx.z;
  if (SWZ) {
    const int lin = blockIdx.x + gridDim.x * (blockIdx.y + gridDim.y * blockIdx.z);
    const int c = lin & 7;      // XCD under round-robin dispatch
    const int i = lin >> 3;     // per-XCD block index
    bz = c;
    bx = i % gridDim.x;
    by = i / gridDim.x;
  }

  A  += (size_t)bz * strideA;
  Bt += (size_t)bz * strideB;

  const int m0 = by * 256;
  const int n0 = bx * BN;
  const int t    = threadIdx.x;
  const int lane = t & 63;
  const int wave = t >> 6;
  const int wm   = (wave >> 2) * 128;
  const int wn   = (wave & 3) * (BN / 4);
  const int lm   = lane & 15;
  const int quad = lane >> 4;
  const int cq   = quad ^ ((lm >> 1) & 3);

  f32x4 acc[8][NF];
#pragma unroll
  for (int i = 0; i < 8; ++i)
#pragma unroll
    for (int j = 0; j < NF; ++j) acc[i][j] = f32x4{0.f, 0.f, 0.f, 0.f};

  const u16* Ag = A + (size_t)m0 * K;
  const u16* Bg = Bt + (size_t)n0 * K;

  const int nk = K >> 5;

  stage32<256>(Ag,      K, sA0, t);  stage32<BN>(Bg,      K, sB0, t);
  stage32<256>(Ag + 32, K, sA1, t);  stage32<BN>(Bg + 32, K, sB1, t);

  for (int kt = 0; kt < nk - 4; kt += 4) {
    vmcnt_wait<LPT>(); block_sync();
    stage32<256>(Ag + (size_t)(kt + 2) * 32, K, sA2, t);
    stage32<BN >(Bg + (size_t)(kt + 2) * 32, K, sB2, t);
    compute_tile32<NF>(sA0, sB0, acc, wm, wn, lm, cq);

    vmcnt_wait<LPT>(); block_sync();
    stage32<256>(Ag + (size_t)(kt + 3) * 32, K, sA3, t);
    stage32<BN >(Bg + (size_t)(kt + 3) * 32, K, sB3, t);
    compute_tile32<NF>(sA1, sB1, acc, wm, wn, lm, cq);

    vmcnt_wait<LPT>(); block_sync();
    stage32<256>(Ag + (size_t)(kt + 4) * 32, K, sA0, t);
    stage32<BN >(Bg + (size_t)(kt + 4) * 32, K, sB0, t);
    compute_tile32<NF>(sA2, sB2, acc, wm, wn, lm, cq);

    vmcnt_wait<LPT>(); block_sync();
    stage32<256>(Ag + (size_t)(kt + 5) * 32, K, sA1, t);
    stage32<BN >(Bg + (size_t)(kt + 5) * 32, K, sB1, t);
    compute_tile32<NF>(sA3, sB3, acc, wm, wn, lm, cq);
  }

  vmcnt_wait<LPT>(); block_sync();
  stage32<256>(Ag + (size_t)(nk - 2) * 32, K, sA2, t);
  stage32<BN >(Bg + (size_t)(nk - 2) * 32, K, sB2, t);
  compute_tile32<NF>(sA0, sB0, acc, wm, wn, lm, cq);

  vmcnt_wait<LPT>(); block_sync();
  stage32<256>(Ag + (size_t)(nk - 1) * 32, K, sA3, t);
  stage32<BN >(Bg + (size_t)(nk - 1) * 32, K, sB3, t);
  compute_tile32<NF>(sA1, sB1, acc, wm, wn, lm, cq);

  vmcnt_wait<LPT>(); block_sync();
  compute_tile32<NF>(sA2, sB2, acc, wm, wn, lm, cq);

  vmcnt_wait<0>(); block_sync();
  compute_tile32<NF>(sA3, sB3, acc, wm, wn, lm, cq);

  if (MODE == 0) {
    u16* C = (u16*)Cv + (size_t)bz * strideC;
#pragma unroll
    for (int nf = 0; nf < NF; ++nf) {
      const int col = n0 + wn + nf * 16 + lm;
      const float bv = bias ? bias[col] : 0.f;
#pragma unroll
      for (int mf = 0; mf < 8; ++mf)
#pragma unroll
        for (int r = 0; r < 4; ++r) {
          const int row = m0 + wm + mf * 16 + quad * 4 + r;
          C[(size_t)row * Ncols + col] = f2h(acc[mf][nf][r] + bv);
        }
    }
  } else {
    float* C = (float*)Cv + (size_t)bz * strideC;
#pragma unroll
    for (int nf = 0; nf < NF; ++nf) {
      const int col = n0 + wn + nf * 16 + lm;
#pragma unroll
      for (int mf = 0; mf < 8; ++mf)
#pragma unroll
        for (int r = 0; r < 4; ++r) {
          const int row = m0 + wm + mf * 16 + quad * 4 + r;
          float v = acc[mf][nf][r];
          if (MODE == 2) v = v > 0.f ? v : expm1f(v);
          C[(size_t)row * Ncols + col] = v;
        }
    }
  }
}

// ---------------------------------------------------------------------------
// masked softmax over one row of 2048: P = softmax(where(adj==0, -inf, S)), fp16 out
// ---------------------------------------------------------------------------
__global__ __launch_bounds__(256) void masked_softmax(
    const float* __restrict__ S, const int* __restrict__ adj, u16* __restrict__ P)
{
  const size_t row = blockIdx.x;
  const float* s = S + row * 2048;
  const int*   a = adj + row * 2048;
  u16*         p = P + row * 2048;
  const int t = threadIdx.x;

  float v[8];
#pragma unroll
  for (int i = 0; i < 2; ++i) {
    float4 sv = ((const float4*)s)[t + i * 256];
    int4   av = ((const int4*)a)[t + i * 256];
    v[i * 4 + 0] = av.x ? sv.x : -1e30f;
    v[i * 4 + 1] = av.y ? sv.y : -1e30f;
    v[i * 4 + 2] = av.z ? sv.z : -1e30f;
    v[i * 4 + 3] = av.w ? sv.w : -1e30f;
  }
  float mx = v[0];
#pragma unroll
  for (int i = 1; i < 8; ++i) mx = fmaxf(mx, v[i]);
#pragma unroll
  for (int o = 32; o > 0; o >>= 1) mx = fmaxf(mx, __shfl_xor(mx, o));
  __shared__ float red[4];
  if ((t & 63) == 0) red[t >> 6] = mx;
  __syncthreads();
  mx = fmaxf(fmaxf(red[0], red[1]), fmaxf(red[2], red[3]));
  __syncthreads();

  float e[8]; float sum = 0.f;
#pragma unroll
  for (int i = 0; i < 8; ++i) { e[i] = __expf(v[i] - mx); sum += e[i]; }
#pragma unroll
  for (int o = 32; o > 0; o >>= 1) sum += __shfl_xor(sum, o);
  if ((t & 63) == 0) red[t >> 6] = sum;
  __syncthreads();
  sum = red[0] + red[1] + red[2] + red[3];
  const float inv = 1.f / sum;

#pragma unroll
  for (int i = 0; i < 2; ++i) {
    u16x4 o4;
    o4[0] = f2h(e[i * 4 + 0] * inv);
    o4[1] = f2h(e[i * 4 + 1] * inv);
    o4[2] = f2h(e[i * 4 + 2] * inv);
    o4[3] = f2h(e[i * 4 + 3] * inv);
    ((u16x4*)p)[t + i * 256] = o4;
  }
}

// ---------------------------------------------------------------------------
// 16-bit transpose per batch (z): in [R][C] -> out [C][R], 64x64 LDS tiles
// ---------------------------------------------------------------------------
__global__ __launch_bounds__(256) void transpose_u16(
    const u16* __restrict__ in, u16* __restrict__ outp, int R, int C)
{
  __shared__ u16 tile[64][65];
  const size_t base = (size_t)blockIdx.z * R * C;
  const int r0 = blockIdx.y * 64, c0 = blockIdx.x * 64;
  const int t = threadIdx.x;
  const int c = t & 63, rr = t >> 6;
#pragma unroll
  for (int i = 0; i < 16; ++i) {
    const int r = rr + i * 4;
    tile[r][c] = in[base + (size_t)(r0 + r) * C + c0 + c];
  }
  __syncthreads();
  const int rp = t & 63, cc = t >> 6;
#pragma unroll
  for (int i = 0; i < 16; ++i) {
    const int cq2 = cc + i * 4;
    outp[base + (size_t)(c0 + cq2) * R + r0 + rp] = tile[rp][cq2];
  }
}

__global__ __launch_bounds__(256) void cvt_f32_f16(
    const float* __restrict__ in, u16* __restrict__ outp, int n4)
{
  const int i = blockIdx.x * 256 + threadIdx.x;
  if (i >= n4) return;
  float4 v = ((const float4*)in)[i];
  u16x4 o; o[0] = f2h(v.x); o[1] = f2h(v.y); o[2] = f2h(v.z); o[3] = f2h(v.w);
  ((u16x4*)outp)[i] = o;
}

// out[j*R + i] = fp16(in[i*C + j])  (coalesced reads, tiny matrix)
__global__ __launch_bounds__(256) void transpose_cvt(
    const float* __restrict__ in, u16* __restrict__ outp, int R, int C)
{
  const int idx = blockIdx.x * 256 + threadIdx.x;
  const int i = idx / C, j = idx % C;
  outp[(size_t)j * R + i] = f2h(in[idx]);
}

// ---------------------------------------------------------------------------
extern "C" void kernel_launch(void* const* d_in, const int* in_sizes, int n_in,
                              void* d_out, int out_size, void* d_ws, size_t ws_size,
                              hipStream_t stream) {
  (void)in_sizes; (void)n_in; (void)out_size;
  const float* x    = (const float*)d_in[0];
  const int*   adj  = (const int*)d_in[1];
  const float* W    = (const float*)d_in[2];
  const float* bvec = (const float*)d_in[3];
  const float* attn = (const float*)d_in[4];
  float* out = (float*)d_out;

  constexpr int B = 8, N = 2048, D = 512;
  constexpr size_t MN = (size_t)B * N;  // 16384

  char* ws = (char*)d_ws;
  size_t off = 0;
  auto take = [&](size_t bytes) -> char* {
    char* p = ws + off;
    off += (bytes + 255) & ~(size_t)255;
    return p;
  };
  u16* xh   = (u16*)take(MN * D * 2);
  u16* Wh   = (u16*)take((size_t)D * D * 2);
  u16* attT = (u16*)take((size_t)D * D * 2);
  u16* h    = (u16*)take(MN * D * 2);
  u16* hT   = (u16*)take(MN * D * 2);
  u16* ha   = (u16*)take(MN * D * 2);

  auto al = [](size_t b) { return (b + 255) & ~(size_t)255; };
  const size_t szSf = al((size_t)B * N * N * 4), szPf = al((size_t)B * N * N * 2);
  const size_t szSb = al((size_t)N * N * 4),     szPb = al((size_t)N * N * 2);
  const bool full  = ws_size >= off + szSf + szPf;
  const bool ok_pb = ws_size >= off + szSb + szPb;
  if (!full && !ok_pb) return;  // ws too small; fail validation cleanly

  // converts
  cvt_f32_f16<<<dim3((unsigned)(MN * D / 4 / 256)), 256, 0, stream>>>(x, xh, (int)(MN * D / 4));
  cvt_f32_f16<<<dim3(D * D / 4 / 256), 256, 0, stream>>>(W, Wh, D * D / 4);
  transpose_cvt<<<dim3(D * D / 256), 256, 0, stream>>>(attn, attT, D, D);

  // K1: h = xh . Wh^T + bias   [16384,512] x [512,512]
  gemm32<128, 0, 0><<<dim3(D / 128, MN / 256, 1), 512, 0, stream>>>(
      xh, Wh, h, bvec, (int)MN, D, D, 0, 0, 0);
  // hT per batch: [2048,512] -> [512,2048]
  transpose_u16<<<dim3(D / 64, N / 64, B), 256, 0, stream>>>(h, hT, N, D);
  // K2: ha = h . attT^T
  gemm32<128, 0, 0><<<dim3(D / 128, MN / 256, 1), 512, 0, stream>>>(
      h, attT, ha, nullptr, (int)MN, D, D, 0, 0, 0);

  if (full) {
    float* S = (float*)take(szSf);
    u16*   P = (u16*)take(szPf);
    // K3: S = ha . h^T per batch  (256x256 tiles; XCD-swizzled: 1 batch/XCD)
    gemm32<256, 1, 1><<<dim3(N / 256, N / 256, B), 512, 0, stream>>>(
        ha, h, S, nullptr, N, N, D,
        (long long)N * D, (long long)N * D, (long long)N * N);
    // K4: masked softmax -> P fp16
    masked_softmax<<<dim3((unsigned)(B * N)), 256, 0, stream>>>(S, adj, P);
    // K5: out = elu(P . hT^T) per batch  (XCD-swizzled: 1 batch/XCD)
    gemm32<128, 2, 1><<<dim3(D / 128, N / 256, B), 512, 0, stream>>>(
        P, hT, out, nullptr, N, D, N,
        (long long)N * N, (long long)D * N, (long long)N * D);
  } else {
    float* S = (float*)take(szSb);
    u16*   P = (u16*)take(szPb);
    for (int b = 0; b < B; ++b) {
      gemm32<256, 1, 0><<<dim3(N / 256, N / 256, 1), 512, 0, stream>>>(
          ha + (size_t)b * N * D, h + (size_t)b * N * D, S, nullptr, N, N, D, 0, 0, 0);
      masked_softmax<<<dim3(N), 256, 0, stream>>>(S, adj + (size_t)b * N * N, P);
      gemm32<128, 2, 0><<<dim3(D / 128, N / 256, 1), 512, 0, stream>>>(
          P, hT + (size_t)b * D * N, out + (size_t)b * N * D, nullptr, N, D, N, 0, 0, 0);
    }
  }
}